// Round 1
// baseline (1633.078 us; speedup 1.0000x reference)
//
#include <hip/hip_runtime.h>
#include <cstdint>
#include <cstddef>

// ---------------------------------------------------------------------------
// GATv2 x2 + linear head on MI355X.
// Strategy: CSR build (hist/scan/scatter) -> per-layer {2x node linear,
// edge logits (wave-per-edge), node-parallel softmax+aggregate}, final linear.
// No float atomics anywhere.
// ---------------------------------------------------------------------------

__global__ void hist_kernel(const int* __restrict__ dst, int* __restrict__ deg, int E) {
    int e = blockIdx.x * blockDim.x + threadIdx.x;
    if (e < E) atomicAdd(&deg[dst[e]], 1);
}

// single-block exclusive scan, 1024 threads, 4 elems/thread/chunk
__global__ void scan_kernel(const int* __restrict__ deg, int* __restrict__ rowstart, int n) {
    __shared__ int wsum[16];
    int tid = threadIdx.x;
    int lane = tid & 63, wid = tid >> 6;
    int running = 0;
    const int CHUNK = 4096;
    for (int base = 0; base < n; base += CHUNK) {
        int v[4];
        int s = 0;
#pragma unroll
        for (int j = 0; j < 4; ++j) {
            int i = base + tid * 4 + j;
            v[j] = (i < n) ? deg[i] : 0;
            s += v[j];
        }
        // wave inclusive scan of s
        int incl = s;
#pragma unroll
        for (int off = 1; off < 64; off <<= 1) {
            int t = __shfl_up(incl, off, 64);
            if (lane >= off) incl += t;
        }
        if (lane == 63) wsum[wid] = incl;
        __syncthreads();
        if (wid == 0) {
            int wv = (lane < 16) ? wsum[lane] : 0;
#pragma unroll
            for (int off = 1; off < 16; off <<= 1) {
                int t = __shfl_up(wv, off, 64);
                if (lane >= off) wv += t;
            }
            if (lane < 16) wsum[lane] = wv;
        }
        __syncthreads();
        int wave_excl = (wid == 0) ? 0 : wsum[wid - 1];
        int acc = running + wave_excl + (incl - s);  // exclusive prefix for this thread
#pragma unroll
        for (int j = 0; j < 4; ++j) {
            int i = base + tid * 4 + j;
            if (i < n) rowstart[i] = acc;
            acc += v[j];
        }
        int total = wsum[15];
        __syncthreads();
        running += total;
    }
    if (tid == 0) rowstart[n] = running;
}

__global__ void scatter_kernel(const int* __restrict__ dst, const int* __restrict__ rowstart,
                               int* __restrict__ cursor, int* __restrict__ sorted, int E) {
    int e = blockIdx.x * blockDim.x + threadIdx.x;
    if (e < E) {
        int d = dst[e];
        int p = atomicAdd(&cursor[d], 1);
        sorted[rowstart[d] + p] = e;
    }
}

// y[n,M] = x[n,K] @ W[K,M] + b ; block = NPB*M threads
template <int K, int M, int NPB>
__global__ void linear_kernel(const float* __restrict__ x, const float* __restrict__ W,
                              const float* __restrict__ b, float* __restrict__ y, int n) {
    __shared__ float sx[NPB * K];
    int tid = threadIdx.x;
    int node0 = blockIdx.x * NPB;
    for (int i = tid; i < NPB * K; i += NPB * M) {
        int nn = node0 + i / K;
        sx[i] = (nn < n) ? x[(size_t)nn * K + (i % K)] : 0.f;
    }
    __syncthreads();
    int ln = tid / M, m = tid % M;
    int node = node0 + ln;
    if (node >= n) return;
    float acc = b[m];
#pragma unroll
    for (int k = 0; k < K; ++k) acc = fmaf(sx[ln * K + k], W[k * M + m], acc);
    y[(size_t)node * M + m] = acc;
}

// e[E,H]: one (64/HC)-edge group per wave; lane -> channel ch = h*C+c
template <int H, int C>
__global__ void edge_logits_kernel(const int* __restrict__ src, const int* __restrict__ dst,
                                   const float* __restrict__ edge_attr,
                                   const float* __restrict__ We, const float* __restrict__ att,
                                   const float* __restrict__ xl, const float* __restrict__ xr,
                                   float* __restrict__ evals, int E) {
    constexpr int HC = H * C;
    constexpr int EPW = 64 / HC;
    int gt = blockIdx.x * blockDim.x + threadIdx.x;
    int wave = gt >> 6;
    int lane = threadIdx.x & 63;
    int sub = lane / HC;  // edge slot within wave
    int ch = lane % HC;   // h*C + c
    int e = wave * EPW + sub;
    bool valid = (e < E);
    int s = 0, d = 0;
    if (valid) { s = src[e]; d = dst[e]; }
    // edge_attr broadcast: lanes ch<16 of each slot hold a[k]
    float aval = 0.f;
    if (valid && ch < 16) aval = edge_attr[(size_t)e * 16 + ch];
    float ea = 0.f;
#pragma unroll
    for (int k = 0; k < 16; ++k) {
        float ak = __shfl(aval, sub * HC + k, 64);
        ea = fmaf(ak, We[k * HC + ch], ea);
    }
    float m = 0.f;
    if (valid) m = xl[(size_t)s * HC + ch] + xr[(size_t)d * HC + ch] + ea;
    m = (m > 0.f) ? m : 0.2f * m;      // leaky_relu 0.2
    float v = m * att[ch];
    // reduce over the C(=32)-lane group
#pragma unroll
    for (int msk = 1; msk < C; msk <<= 1) v += __shfl_xor(v, msk, 64);
    if (valid && (lane & (C - 1)) == 0) {
        evals[(size_t)e * H + (ch / C)] = v;
    }
}

// per-node softmax + weighted aggregation + bias + ELU
template <int H, int C>
__global__ void node_agg_kernel(const int* __restrict__ rowstart, const int* __restrict__ sorted,
                                const int* __restrict__ src, const float* __restrict__ evals,
                                const float* __restrict__ xl, const float* __restrict__ bias,
                                float* __restrict__ out, int n) {
    constexpr int HC = H * C;
    constexpr int NPW = 64 / HC;
    int gt = blockIdx.x * blockDim.x + threadIdx.x;
    int wave = gt >> 6;
    int lane = threadIdx.x & 63;
    int sub = lane / HC;
    int ch = lane % HC;
    int node = wave * NPW + sub;
    if (node >= n) return;
    int h = ch / C;
    int beg = rowstart[node], end = rowstart[node + 1];
    float mx = -INFINITY;
    for (int p = beg; p < end; ++p) {
        int eid = sorted[p];
        mx = fmaxf(mx, evals[(size_t)eid * H + h]);
    }
    float denom = 0.f, acc = 0.f;
    for (int p = beg; p < end; ++p) {
        int eid = sorted[p];
        float w = __expf(evals[(size_t)eid * H + h] - mx);
        denom += w;
        acc = fmaf(xl[(size_t)src[eid] * HC + ch], w, acc);
    }
    float o = acc / (denom + 1e-16f) + bias[ch];
    out[(size_t)node * HC + ch] = (o > 0.f) ? o : (__expf(o) - 1.f);
}

extern "C" void kernel_launch(void* const* d_in, const int* in_sizes, int n_in,
                              void* d_out, int out_size, void* d_ws, size_t ws_size,
                              hipStream_t stream) {
    const float* x        = (const float*)d_in[0];
    const int*   eidx     = (const int*)d_in[1];
    const float* eattr    = (const float*)d_in[2];
    const float* W1l      = (const float*)d_in[3];
    const float* b1l      = (const float*)d_in[4];
    const float* W1r      = (const float*)d_in[5];
    const float* b1r      = (const float*)d_in[6];
    const float* W1e      = (const float*)d_in[7];
    const float* att1     = (const float*)d_in[8];
    const float* bias1    = (const float*)d_in[9];
    const float* W2l      = (const float*)d_in[10];
    const float* b2l      = (const float*)d_in[11];
    const float* W2r      = (const float*)d_in[12];
    const float* b2r      = (const float*)d_in[13];
    const float* W2e      = (const float*)d_in[14];
    const float* att2     = (const float*)d_in[15];
    const float* bias2    = (const float*)d_in[16];
    const float* Wlin     = (const float*)d_in[17];
    const float* blin     = (const float*)d_in[18];

    const int N = in_sizes[0] / 128;
    const int E = in_sizes[1] / 2;
    const int* src = eidx;
    const int* dst = eidx + E;

    // workspace carve (256B aligned)
    char* p = (char*)d_ws;
    auto take = [&](size_t bytes) {
        char* r = p;
        p += (bytes + 255) & ~(size_t)255;
        return r;
    };
    int*   deg      = (int*)take((size_t)N * sizeof(int));
    int*   cursor   = (int*)take((size_t)N * sizeof(int));
    int*   rowstart = (int*)take((size_t)(N + 1) * sizeof(int));
    int*   sorted   = (int*)take((size_t)E * sizeof(int));
    float* A        = (float*)take((size_t)N * 64 * sizeof(float));  // xl1 / xl2
    float* B        = (float*)take((size_t)N * 64 * sizeof(float));  // xr1 / xr2
    float* Cbuf     = (float*)take((size_t)N * 64 * sizeof(float));  // h1 / h2
    float* Ebuf     = (float*)take((size_t)E * 2 * sizeof(float));   // logits

    // ---- CSR build (reused by both layers) ----
    hipMemsetAsync(deg, 0, (size_t)N * sizeof(int), stream);
    hipMemsetAsync(cursor, 0, (size_t)N * sizeof(int), stream);
    hist_kernel<<<(E + 255) / 256, 256, 0, stream>>>(dst, deg, E);
    scan_kernel<<<1, 1024, 0, stream>>>(deg, rowstart, N);
    scatter_kernel<<<(E + 255) / 256, 256, 0, stream>>>(dst, rowstart, cursor, sorted, E);

    // ---- Layer 1: H=2, C=32 (HC=64) ----
    linear_kernel<128, 64, 4><<<(N + 3) / 4, 256, 0, stream>>>(x, W1l, b1l, A, N);
    linear_kernel<128, 64, 4><<<(N + 3) / 4, 256, 0, stream>>>(x, W1r, b1r, B, N);
    {
        int waves = E;  // 1 edge per wave
        int grid = (waves * 64 + 255) / 256;
        edge_logits_kernel<2, 32><<<grid, 256, 0, stream>>>(src, dst, eattr, W1e, att1, A, B, Ebuf, E);
    }
    node_agg_kernel<2, 32><<<((size_t)N * 64 + 255) / 256, 256, 0, stream>>>(
        rowstart, sorted, src, Ebuf, A, bias1, Cbuf, N);

    // ---- Layer 2: H=1, C=32 (HC=32), input h1=Cbuf ----
    linear_kernel<64, 32, 8><<<(N + 7) / 8, 256, 0, stream>>>(Cbuf, W2l, b2l, A, N);
    linear_kernel<64, 32, 8><<<(N + 7) / 8, 256, 0, stream>>>(Cbuf, W2r, b2r, B, N);
    {
        int waves = (E + 1) / 2;  // 2 edges per wave
        int grid = (waves * 64 + 255) / 256;
        edge_logits_kernel<1, 32><<<grid, 256, 0, stream>>>(src, dst, eattr, W2e, att2, A, B, Ebuf, E);
    }
    node_agg_kernel<1, 32><<<((size_t)N * 32 + 255) / 256, 256, 0, stream>>>(
        rowstart, sorted, src, Ebuf, A, bias2, Cbuf, N);

    // ---- Final linear: h2 @ Wlin + blin -> d_out ----
    linear_kernel<32, 32, 8><<<(N + 7) / 8, 256, 0, stream>>>(Cbuf, Wlin, blin, (float*)d_out, N);
}

// Round 2
// 935.025 us; speedup vs baseline: 1.7466x; 1.7466x over previous
//
#include <hip/hip_runtime.h>
#include <cstdint>
#include <cstddef>

// ---------------------------------------------------------------------------
// GATv2 x2 + linear head on MI355X.
// CSR build (hist/scan/scatter, also materializes src_sorted) ->
// per-layer { fused dual linear, edge logits in dst-sorted order (grid-stride,
// 2ch/lane, We in regs), single-pass node softmax+aggregate (no max pass) },
// final linear. No float atomics.
// ---------------------------------------------------------------------------

__global__ void hist_kernel(const int* __restrict__ dst, int* __restrict__ deg, int E) {
    int e = blockIdx.x * blockDim.x + threadIdx.x;
    if (e < E) atomicAdd(&deg[dst[e]], 1);
}

// single-block exclusive scan, 1024 threads, 4 elems/thread/chunk
__global__ void scan_kernel(const int* __restrict__ deg, int* __restrict__ rowstart, int n) {
    __shared__ int wsum[16];
    int tid = threadIdx.x;
    int lane = tid & 63, wid = tid >> 6;
    int running = 0;
    const int CHUNK = 4096;
    for (int base = 0; base < n; base += CHUNK) {
        int v[4];
        int s = 0;
#pragma unroll
        for (int j = 0; j < 4; ++j) {
            int i = base + tid * 4 + j;
            v[j] = (i < n) ? deg[i] : 0;
            s += v[j];
        }
        int incl = s;
#pragma unroll
        for (int off = 1; off < 64; off <<= 1) {
            int t = __shfl_up(incl, off, 64);
            if (lane >= off) incl += t;
        }
        if (lane == 63) wsum[wid] = incl;
        __syncthreads();
        if (wid == 0) {
            int wv = (lane < 16) ? wsum[lane] : 0;
#pragma unroll
            for (int off = 1; off < 16; off <<= 1) {
                int t = __shfl_up(wv, off, 64);
                if (lane >= off) wv += t;
            }
            if (lane < 16) wsum[lane] = wv;
        }
        __syncthreads();
        int wave_excl = (wid == 0) ? 0 : wsum[wid - 1];
        int acc = running + wave_excl + (incl - s);
#pragma unroll
        for (int j = 0; j < 4; ++j) {
            int i = base + tid * 4 + j;
            if (i < n) rowstart[i] = acc;
            acc += v[j];
        }
        int total = wsum[15];
        __syncthreads();
        running += total;
    }
    if (tid == 0) rowstart[n] = running;
}

__global__ void scatter_kernel(const int* __restrict__ src, const int* __restrict__ dst,
                               const int* __restrict__ rowstart, int* __restrict__ cursor,
                               int* __restrict__ sorted, int* __restrict__ src_sorted, int E) {
    int e = blockIdx.x * blockDim.x + threadIdx.x;
    if (e < E) {
        int d = dst[e];
        int p = atomicAdd(&cursor[d], 1);
        int pos = rowstart[d] + p;
        sorted[pos] = e;
        src_sorted[pos] = src[e];
    }
}

// yl = x@Wl+bl, yr = x@Wr+br in one pass over x; block = NPB*M threads
template <int K, int M, int NPB>
__global__ void linear2_kernel(const float* __restrict__ x,
                               const float* __restrict__ Wl, const float* __restrict__ bl,
                               const float* __restrict__ Wr, const float* __restrict__ br,
                               float* __restrict__ yl, float* __restrict__ yr, int n) {
    __shared__ float sx[NPB * K];
    int tid = threadIdx.x;
    int node0 = blockIdx.x * NPB;
    for (int i = tid; i < NPB * K; i += NPB * M) {
        int nn = node0 + i / K;
        sx[i] = (nn < n) ? x[(size_t)nn * K + (i % K)] : 0.f;
    }
    __syncthreads();
    int ln = tid / M, m = tid % M;
    int node = node0 + ln;
    if (node >= n) return;
    float accL = bl[m], accR = br[m];
#pragma unroll
    for (int k = 0; k < K; ++k) {
        float xv = sx[ln * K + k];
        accL = fmaf(xv, Wl[k * M + m], accL);
        accR = fmaf(xv, Wr[k * M + m], accR);
    }
    yl[(size_t)node * M + m] = accL;
    yr[(size_t)node * M + m] = accR;
}

// y[n,M] = x[n,K] @ W[K,M] + b ; block = NPB*M threads
template <int K, int M, int NPB>
__global__ void linear_kernel(const float* __restrict__ x, const float* __restrict__ W,
                              const float* __restrict__ b, float* __restrict__ y, int n) {
    __shared__ float sx[NPB * K];
    int tid = threadIdx.x;
    int node0 = blockIdx.x * NPB;
    for (int i = tid; i < NPB * K; i += NPB * M) {
        int nn = node0 + i / K;
        sx[i] = (nn < n) ? x[(size_t)nn * K + (i % K)] : 0.f;
    }
    __syncthreads();
    int ln = tid / M, m = tid % M;
    int node = node0 + ln;
    if (node >= n) return;
    float acc = b[m];
#pragma unroll
    for (int k = 0; k < K; ++k) acc = fmaf(sx[ln * K + k], W[k * M + m], acc);
    y[(size_t)node * M + m] = acc;
}

// Edge logits over dst-sorted edge order. 2 channels/lane; grid-stride waves.
// Writes evals[p*H + h] where p is the sorted position.
template <int H, int C>
__global__ void edge_logits_sorted(const int* __restrict__ sorted,
                                   const int* __restrict__ src_sorted,
                                   const int* __restrict__ dst,
                                   const float* __restrict__ edge_attr,
                                   const float* __restrict__ We,   // [16, HC]
                                   const float* __restrict__ att,  // [HC]
                                   const float* __restrict__ xl, const float* __restrict__ xr,
                                   float* __restrict__ evals, int E) {
    constexpr int HC = H * C;
    constexpr int LPE = HC / 2;   // lanes per edge (2 ch each)
    constexpr int EPW = 64 / LPE; // edges per wave
    int lane = threadIdx.x & 63;
    int sub = lane / LPE;
    int j = lane % LPE;
    int ch0 = 2 * j;
    int head = ch0 / C;
    // hoist We column + att into registers (amortized over many edges)
    float2 wcol[16];
#pragma unroll
    for (int k = 0; k < 16; ++k) wcol[k] = *(const float2*)&We[k * HC + ch0];
    float2 a2 = *(const float2*)&att[ch0];

    int wave = (blockIdx.x * blockDim.x + threadIdx.x) >> 6;
    int nwaves = (gridDim.x * blockDim.x) >> 6;
    int ngroups = (E + EPW - 1) / EPW;
    for (int g = wave; g < ngroups; g += nwaves) {
        int p = g * EPW + sub;
        bool valid = (p < E);
        int pc = valid ? p : (E - 1);
        int eid = sorted[pc];
        int s = src_sorted[pc];
        int d = dst[eid];
        const float4* ea4 = (const float4*)&edge_attr[(size_t)eid * 16];
        float4 e0 = ea4[0], e1 = ea4[1], e2 = ea4[2], e3 = ea4[3];
        float2 xlv = *(const float2*)&xl[(size_t)s * HC + ch0];
        float2 xrv = *(const float2*)&xr[(size_t)d * HC + ch0];
        float av[16] = {e0.x, e0.y, e0.z, e0.w, e1.x, e1.y, e1.z, e1.w,
                        e2.x, e2.y, e2.z, e2.w, e3.x, e3.y, e3.z, e3.w};
        float m0 = xlv.x + xrv.x;
        float m1 = xlv.y + xrv.y;
#pragma unroll
        for (int k = 0; k < 16; ++k) {
            m0 = fmaf(av[k], wcol[k].x, m0);
            m1 = fmaf(av[k], wcol[k].y, m1);
        }
        m0 = (m0 > 0.f) ? m0 : 0.2f * m0;
        m1 = (m1 > 0.f) ? m1 : 0.2f * m1;
        float v = m0 * a2.x + m1 * a2.y;
        // sum over the 16-lane head group
#pragma unroll
        for (int msk = 1; msk < 16; msk <<= 1) v += __shfl_xor(v, msk, 64);
        if (valid && (j & 15) == 0) evals[(size_t)p * H + head] = v;
    }
}

// Single-pass per-node softmax + weighted aggregation (+bias, ELU).
// Reads evals/src_sorted as streams; 2 channels/lane.
template <int H, int C>
__global__ void node_agg_sorted(const int* __restrict__ rowstart,
                                const int* __restrict__ src_sorted,
                                const float* __restrict__ evals,
                                const float* __restrict__ xl,
                                const float* __restrict__ bias,
                                float* __restrict__ out, int n) {
    constexpr int HC = H * C;
    constexpr int LPN = HC / 2;
    constexpr int NPW = 64 / LPN;
    int gt = blockIdx.x * blockDim.x + threadIdx.x;
    int wave = gt >> 6;
    int lane = threadIdx.x & 63;
    int sub = lane / LPN;
    int j = lane % LPN;
    int ch0 = 2 * j;
    int head = ch0 / C;
    int node = wave * NPW + sub;
    if (node >= n) return;
    int beg = rowstart[node], end = rowstart[node + 1];
    float denom = 0.f, acc0 = 0.f, acc1 = 0.f;
    for (int p = beg; p < end; ++p) {
        float w = __expf(evals[(size_t)p * H + head]);
        int s = src_sorted[p];
        float2 xv = *(const float2*)&xl[(size_t)s * HC + ch0];
        denom += w;
        acc0 = fmaf(xv.x, w, acc0);
        acc1 = fmaf(xv.y, w, acc1);
    }
    float2 b2 = *(const float2*)&bias[ch0];
    float inv = 1.f / (denom + 1e-16f);
    float o0 = acc0 * inv + b2.x;
    float o1 = acc1 * inv + b2.y;
    o0 = (o0 > 0.f) ? o0 : __expf(o0) - 1.f;
    o1 = (o1 > 0.f) ? o1 : __expf(o1) - 1.f;
    *(float2*)&out[(size_t)node * HC + ch0] = make_float2(o0, o1);
}

extern "C" void kernel_launch(void* const* d_in, const int* in_sizes, int n_in,
                              void* d_out, int out_size, void* d_ws, size_t ws_size,
                              hipStream_t stream) {
    const float* x     = (const float*)d_in[0];
    const int*   eidx  = (const int*)d_in[1];
    const float* eattr = (const float*)d_in[2];
    const float* W1l   = (const float*)d_in[3];
    const float* b1l   = (const float*)d_in[4];
    const float* W1r   = (const float*)d_in[5];
    const float* b1r   = (const float*)d_in[6];
    const float* W1e   = (const float*)d_in[7];
    const float* att1  = (const float*)d_in[8];
    const float* bias1 = (const float*)d_in[9];
    const float* W2l   = (const float*)d_in[10];
    const float* b2l   = (const float*)d_in[11];
    const float* W2r   = (const float*)d_in[12];
    const float* b2r   = (const float*)d_in[13];
    const float* W2e   = (const float*)d_in[14];
    const float* att2  = (const float*)d_in[15];
    const float* bias2 = (const float*)d_in[16];
    const float* Wlin  = (const float*)d_in[17];
    const float* blin  = (const float*)d_in[18];

    const int N = in_sizes[0] / 128;
    const int E = in_sizes[1] / 2;
    const int* src = eidx;
    const int* dst = eidx + E;

    char* p = (char*)d_ws;
    auto take = [&](size_t bytes) {
        char* r = p;
        p += (bytes + 255) & ~(size_t)255;
        return r;
    };
    int*   deg        = (int*)take((size_t)N * sizeof(int));
    int*   cursor     = (int*)take((size_t)N * sizeof(int));
    int*   rowstart   = (int*)take((size_t)(N + 1) * sizeof(int));
    int*   sorted     = (int*)take((size_t)E * sizeof(int));
    int*   src_sorted = (int*)take((size_t)E * sizeof(int));
    float* A          = (float*)take((size_t)N * 64 * sizeof(float));  // xl
    float* B          = (float*)take((size_t)N * 64 * sizeof(float));  // xr
    float* Cbuf       = (float*)take((size_t)N * 64 * sizeof(float));  // h1 / h2
    float* Ebuf       = (float*)take((size_t)E * 2 * sizeof(float));   // logits (sorted order)

    // ---- CSR build ----
    hipMemsetAsync(deg, 0, (size_t)N * sizeof(int), stream);
    hipMemsetAsync(cursor, 0, (size_t)N * sizeof(int), stream);
    hist_kernel<<<(E + 255) / 256, 256, 0, stream>>>(dst, deg, E);
    scan_kernel<<<1, 1024, 0, stream>>>(deg, rowstart, N);
    scatter_kernel<<<(E + 255) / 256, 256, 0, stream>>>(src, dst, rowstart, cursor, sorted,
                                                        src_sorted, E);

    const int EDGE_GRID = 2048;  // persistent grid-stride waves

    // ---- Layer 1: H=2, C=32 ----
    linear2_kernel<128, 64, 4><<<(N + 3) / 4, 256, 0, stream>>>(x, W1l, b1l, W1r, b1r, A, B, N);
    edge_logits_sorted<2, 32><<<EDGE_GRID, 256, 0, stream>>>(sorted, src_sorted, dst, eattr, W1e,
                                                             att1, A, B, Ebuf, E);
    node_agg_sorted<2, 32><<<((size_t)(N + 1) / 2 * 64 + 255) / 256, 256, 0, stream>>>(
        rowstart, src_sorted, Ebuf, A, bias1, Cbuf, N);

    // ---- Layer 2: H=1, C=32 ----
    linear2_kernel<64, 32, 8><<<(N + 7) / 8, 256, 0, stream>>>(Cbuf, W2l, b2l, W2r, b2r, A, B, N);
    edge_logits_sorted<1, 32><<<EDGE_GRID, 256, 0, stream>>>(sorted, src_sorted, dst, eattr, W2e,
                                                             att2, A, B, Ebuf, E);
    node_agg_sorted<1, 32><<<((size_t)(N + 3) / 4 * 64 + 255) / 256, 256, 0, stream>>>(
        rowstart, src_sorted, Ebuf, A, bias2, Cbuf, N);

    // ---- Final linear ----
    linear_kernel<32, 32, 8><<<(N + 7) / 8, 256, 0, stream>>>(Cbuf, Wlin, blin, (float*)d_out, N);
}